// Round 2
// baseline (479.141 us; speedup 1.0000x reference)
//
#include <hip/hip_runtime.h>
#include <hip/hip_bf16.h>
#include <stdint.h>

#define B_ 64
#define N_ 4096
#define D_ 128
#define S_ 7
#define EPS_ 1e-8f
#define LN_EPS_ 1e-5f

typedef float  f32x4  __attribute__((ext_vector_type(4)));
typedef __bf16 bf16x8 __attribute__((ext_vector_type(8)));

__device__ __forceinline__ uint16_t f2bfbits(float f) {
    uint32_t x = __float_as_uint(f);
    return (uint16_t)((x + 0x7fffu + ((x >> 16) & 1u)) >> 16);  // RNE
}
__device__ __forceinline__ uint32_t pk2(float a, float b) {
    return (uint32_t)f2bfbits(a) | ((uint32_t)f2bfbits(b) << 16);
}

// ---------------------------------------------------------------------------
// K0: slots = mu + (softplus(logsigma)+1e-5)*noise; zero padded q rows;
//     Wsw = [Wk;Wv] in MFMA fragment-linear order:
//     elem = ((h*8+wt)*4+k0)*512 + lane*8 + j  <->  W[wt*16+(lane&15)][k0*32+(lane>>4)*8+j]
// ---------------------------------------------------------------------------
__global__ void k_prep(const float* __restrict__ noise, const float* __restrict__ Wk,
                       const float* __restrict__ Wv, const float* __restrict__ mu,
                       const float* __restrict__ logsigma,
                       uint16_t* __restrict__ Wsw, float* __restrict__ slots,
                       uint16_t* __restrict__ qbf) {
    int tid = blockIdx.x * 256 + threadIdx.x;
    if (tid < B_ * 16 * D_) qbf[tid] = 0;
    if (tid < B_ * S_ * D_) {
        int d = tid & (D_ - 1);
        float sc = log1pf(__expf(logsigma[d])) + 1e-5f;
        slots[tid] = mu[d] + sc * noise[tid];
    }
    if (tid < 32768) {
        int j = tid & 7, ch = tid >> 3;
        int lane = ch & 63, k0 = (ch >> 6) & 3, wt = (ch >> 8) & 7, h = ch >> 11;
        int row = wt * 16 + (lane & 15);
        int col = k0 * 32 + (lane >> 4) * 8 + j;
        float w = h ? Wv[row * 128 + col] : Wk[row * 128 + col];
        Wsw[tid] = f2bfbits(w);
    }
}

// ---------------------------------------------------------------------------
// K1: LN(x) in registers -> bf16 B-frags; K-half: C=Wk*xn^T -> kbf[row][d]
//     (8B stores); V-half: C=xn*Wv^T -> vbf_t[b][d][n] (8B stores).
//     Weight frags staged to LDS from pre-swizzled Wsw: reads are
//     base+lane*16 -> conflict-free.
// ---------------------------------------------------------------------------
__global__ __launch_bounds__(256, 4) void k_proj(
    const float* __restrict__ x, const uint16_t* __restrict__ Wsw,
    const float* __restrict__ lng, const float* __restrict__ lnb,
    uint16_t* __restrict__ kbf, uint16_t* __restrict__ vbf_t) {
    __shared__ __align__(16) uint16_t wlds[16384];  // 32 KB: one half, frag-linear
    const int t = threadIdx.x, wv = t >> 6, lane = t & 63;
    const int lm = lane & 15, qd = lane >> 4;
    const long row0 = (long)blockIdx.x * 64;
    const int b = (int)(row0 >> 12);
    const int nloc = (int)(row0 & 4095);

    // stage half 0 (Wk frags): global -> regs
    uint4 wst[8];
    #pragma unroll
    for (int i = 0; i < 8; ++i)
        wst[i] = *(const uint4*)(Wsw + (i * 256 + t) * 8);

    // x loads: lane (lm,qd) owns row (wv*16+lm), elements k0*32+qd*8+(0..7)
    const long xrow = row0 + wv * 16 + lm;
    const float* xp = x + xrow * 128 + qd * 8;
    f32x4 xa[8];
    #pragma unroll
    for (int k0 = 0; k0 < 4; ++k0) {
        xa[2 * k0]     = *(const f32x4*)(xp + k0 * 32);
        xa[2 * k0 + 1] = *(const f32x4*)(xp + k0 * 32 + 4);
    }
    // regs -> LDS (contiguous, conflict-free)
    #pragma unroll
    for (int i = 0; i < 8; ++i)
        *(uint4*)(wlds + (i * 256 + t) * 8) = wst[i];

    // LN stats: row split across 4 qd-lanes -> 2 shuffles
    float s = 0.f, sq = 0.f;
    #pragma unroll
    for (int i = 0; i < 8; ++i)
        #pragma unroll
        for (int c = 0; c < 4; ++c) { float v = xa[i][c]; s += v; sq += v * v; }
    s  += __shfl_xor(s, 16);  s  += __shfl_xor(s, 32);
    sq += __shfl_xor(sq, 16); sq += __shfl_xor(sq, 32);
    float mean = s * (1.0f / 128.0f);
    float var  = sq * (1.0f / 128.0f) - mean * mean;
    float rs   = rsqrtf(var + LN_EPS_);

    bf16x8 xf[4];
    #pragma unroll
    for (int k0 = 0; k0 < 4; ++k0) {
        const float* gp = lng + k0 * 32 + qd * 8;
        const float* bp = lnb + k0 * 32 + qd * 8;
        f32x4 g0 = *(const f32x4*)(gp), g1 = *(const f32x4*)(gp + 4);
        f32x4 b0 = *(const f32x4*)(bp), b1 = *(const f32x4*)(bp + 4);
        #pragma unroll
        for (int c = 0; c < 4; ++c) {
            ((__bf16*)&xf[k0])[c]     = (__bf16)((xa[2 * k0][c]     - mean) * rs * g0[c] + b0[c]);
            ((__bf16*)&xf[k0])[4 + c] = (__bf16)((xa[2 * k0 + 1][c] - mean) * rs * g1[c] + b1[c]);
        }
    }
    __syncthreads();

    // K-half: mfma(A=w, B=x) -> C[d][xrow]; lane holds 4 consecutive d
    #pragma unroll
    for (int mt = 0; mt < 8; ++mt) {
        f32x4 acc = {0.f, 0.f, 0.f, 0.f};
        #pragma unroll
        for (int k0 = 0; k0 < 4; ++k0) {
            bf16x8 wf = *(const bf16x8*)(wlds + ((mt * 4 + k0) * 64 + lane) * 8);
            acc = __builtin_amdgcn_mfma_f32_16x16x32_bf16(wf, xf[k0], acc, 0, 0, 0);
        }
        uint2 st; st.x = pk2(acc[0], acc[1]); st.y = pk2(acc[2], acc[3]);
        *(uint2*)(kbf + (row0 + wv * 16 + lm) * 128 + mt * 16 + qd * 4) = st;
    }
    __syncthreads();

    // stage half 1 (Wv frags)
    #pragma unroll
    for (int i = 0; i < 8; ++i)
        wst[i] = *(const uint4*)(Wsw + 16384 + (i * 256 + t) * 8);
    #pragma unroll
    for (int i = 0; i < 8; ++i)
        *(uint4*)(wlds + (i * 256 + t) * 8) = wst[i];
    __syncthreads();

    // V-half: mfma(A=x, B=w) -> C[xrow][d]; lane holds 4 consecutive n -> vbf_t
    #pragma unroll
    for (int nt = 0; nt < 8; ++nt) {
        f32x4 acc = {0.f, 0.f, 0.f, 0.f};
        #pragma unroll
        for (int k0 = 0; k0 < 4; ++k0) {
            bf16x8 wf = *(const bf16x8*)(wlds + ((nt * 4 + k0) * 64 + lane) * 8);
            acc = __builtin_amdgcn_mfma_f32_16x16x32_bf16(xf[k0], wf, acc, 0, 0, 0);
        }
        uint2 st; st.x = pk2(acc[0], acc[1]); st.y = pk2(acc[2], acc[3]);
        *(uint2*)(vbf_t + ((long)(b * 128 + nt * 16 + lm)) * 4096 + nloc + wv * 16 + qd * 4) = st;
    }
}

// ---------------------------------------------------------------------------
// K2: per (b,s): sn = LN(slots); q = (sn @ Wq^T) * D^-1/2 -> bf16; zero
//     upraw/colsum for this iteration.
// ---------------------------------------------------------------------------
__global__ __launch_bounds__(128) void k_slotq(
    const float* __restrict__ slots, const float* __restrict__ Wq,
    const float* __restrict__ g, const float* __restrict__ bt,
    uint16_t* __restrict__ qbf, float* __restrict__ colsum, float* __restrict__ upraw) {
    int row = blockIdx.x;  // b*7 + s
    int b = row / 7, s = row - b * 7;
    int t = threadIdx.x;
    __shared__ float sn[128];
    __shared__ float red[2];
    float v = slots[row * 128 + t];
    float sv = v;
    #pragma unroll
    for (int m = 1; m < 64; m <<= 1) sv += __shfl_xor(sv, m);
    if ((t & 63) == 0) red[t >> 6] = sv;
    __syncthreads();
    float mean = (red[0] + red[1]) * (1.0f / 128.0f);
    __syncthreads();
    float dv = v - mean, sq = dv * dv;
    #pragma unroll
    for (int m = 1; m < 64; m <<= 1) sq += __shfl_xor(sq, m);
    if ((t & 63) == 0) red[t >> 6] = sq;
    __syncthreads();
    float var = (red[0] + red[1]) * (1.0f / 128.0f);
    sn[t] = dv * rsqrtf(var + LN_EPS_) * g[t] + bt[t];
    __syncthreads();
    const float4* wr = (const float4*)(Wq + t * 128);
    float acc = 0.f;
    #pragma unroll 8
    for (int j = 0; j < 32; ++j) {
        float4 w = wr[j];
        float4 s4 = *(const float4*)(sn + 4 * j);
        acc += w.x * s4.x + w.y * s4.y + w.z * s4.z + w.w * s4.w;
    }
    qbf[(b * 16 + s) * 128 + t] = f2bfbits(acc * 0.08838834764831843f);  // 1/sqrt(128)
    upraw[row * 128 + t] = 0.f;
    if (t == 0) colsum[row] = 0.f;
}

// ---------------------------------------------------------------------------
// K3: scores via MFMA (A=k rows, B=q padded) -> softmax over S=7 in 16-lane
//     groups -> bf16 attn frags packed into per-wave LDS (8B writes) ->
//     updates = v^T * attn via MFMA (A=vbf_t frags, B=attn frags) ->
//     LDS cross-wave reduce -> atomics into upraw; colsum via 2 shuffles + atomic.
// ---------------------------------------------------------------------------
__global__ __launch_bounds__(256, 4) void k_attn(
    const uint16_t* __restrict__ kbf, const uint16_t* __restrict__ vbf_t,
    const uint16_t* __restrict__ qbf,
    float* __restrict__ colsum, float* __restrict__ upraw) {
    __shared__ __align__(16) uint16_t als[4][1024];   // per-wave attn frags (2 k-chunks)
    __shared__ __align__(16) float part[4][7][132];   // cross-wave update partials
    const int t = threadIdx.x, wv = t >> 6, lane = t & 63;
    const int lm = lane & 15, qd = lane >> 4;
    const int b = blockIdx.x >> 4, chunk = blockIdx.x & 15;
    const int rb = chunk * 256 + wv * 64;       // row base within batch
    const long gbase = (long)b * N_ + rb;

    bf16x8 bq[4];
    #pragma unroll
    for (int k0 = 0; k0 < 4; ++k0)
        bq[k0] = *(const bf16x8*)(qbf + b * 2048 + lm * 128 + k0 * 32 + qd * 8);

    float csl = 0.f;
    #pragma unroll
    for (int mt = 0; mt < 4; ++mt) {
        f32x4 acc = {0.f, 0.f, 0.f, 0.f};
        long rr = gbase + mt * 16;
        #pragma unroll
        for (int k0 = 0; k0 < 4; ++k0) {
            bf16x8 a = *(const bf16x8*)(kbf + (rr + lm) * 128 + k0 * 32 + qd * 8);
            acc = __builtin_amdgcn_mfma_f32_16x16x32_bf16(a, bq[k0], acc, 0, 0, 0);
        }
        uint16_t pb[4];
        #pragma unroll
        for (int r = 0; r < 4; ++r) {
            float sc = acc[r];
            float scm = (lm < 7) ? sc : -1e30f;
            #pragma unroll
            for (int m = 1; m < 16; m <<= 1) scm = fmaxf(scm, __shfl_xor(scm, m));
            float e = (lm < 7) ? __expf(sc - scm) : 0.f;
            float tot = e;
            #pragma unroll
            for (int m = 1; m < 16; m <<= 1) tot += __shfl_xor(tot, m);
            float a_ = e / tot + EPS_;
            if (lm < 7) csl += a_;
            pb[r] = f2bfbits(a_);
        }
        // pack 4 consecutive k-positions of attn^T[s=lm][.] -> frag-linear LDS
        int elem = (mt >> 1) * 512 + (((mt & 1) * 2 + (qd >> 1)) * 16 + lm) * 8 + (qd & 1) * 4;
        uint2 pw; pw.x = (uint32_t)pb[0] | ((uint32_t)pb[1] << 16);
        pw.y = (uint32_t)pb[2] | ((uint32_t)pb[3] << 16);
        *(uint2*)(&als[wv][elem]) = pw;
    }
    csl += __shfl_xor(csl, 16); csl += __shfl_xor(csl, 32);
    if (lane < 7) atomicAdd(&colsum[b * 7 + lane], csl);
    __syncthreads();

    bf16x8 afr0 = *(const bf16x8*)(&als[wv][lane * 8]);         // k-rows [0,32)
    bf16x8 afr1 = *(const bf16x8*)(&als[wv][512 + lane * 8]);   // k-rows [32,64)
    f32x4 uacc[8];
    #pragma unroll
    for (int i = 0; i < 8; ++i) uacc[i] = (f32x4){0.f, 0.f, 0.f, 0.f};
    #pragma unroll
    for (int nt = 0; nt < 8; ++nt) {
        const uint16_t* vp = vbf_t + ((long)(b * 128 + nt * 16 + lm)) * 4096 + rb;
        bf16x8 v0 = *(const bf16x8*)(vp + qd * 8);
        bf16x8 v1 = *(const bf16x8*)(vp + 32 + qd * 8);
        uacc[nt] = __builtin_amdgcn_mfma_f32_16x16x32_bf16(v0, afr0, uacc[nt], 0, 0, 0);
        uacc[nt] = __builtin_amdgcn_mfma_f32_16x16x32_bf16(v1, afr1, uacc[nt], 0, 0, 0);
    }
    if (lm < 7) {
        #pragma unroll
        for (int nt = 0; nt < 8; ++nt)
            *(f32x4*)&part[wv][lm][nt * 16 + qd * 4] = uacc[nt];
    }
    __syncthreads();
    if (t < 128) {
        #pragma unroll
        for (int s = 0; s < 7; ++s) {
            float v = part[0][s][t] + part[1][s][t] + part[2][s][t] + part[3][s][t];
            atomicAdd(&upraw[(b * 7 + s) * 128 + t], v);
        }
    }
}

// ---------------------------------------------------------------------------
// K4: per (b,s) row: u = upraw/colsum; GRU(u, h=slots); LN; slots = sl + MLP(sl)
// ---------------------------------------------------------------------------
__global__ __launch_bounds__(128) void k_gru_mlp(
    const float* __restrict__ upraw, const float* __restrict__ colsum,
    const float* __restrict__ slots_in,
    const float* __restrict__ Wih, const float* __restrict__ Whh,
    const float* __restrict__ bih, const float* __restrict__ bhh,
    const float* __restrict__ gm, const float* __restrict__ bm,
    const float* __restrict__ W1, const float* __restrict__ b1,
    const float* __restrict__ W2, const float* __restrict__ b2,
    float* __restrict__ dst) {
    int row = blockIdx.x, t = threadIdx.x;
    __shared__ float su[128], sh[128], ssl[128], shid[256];
    __shared__ float red[2];
    float inv = 1.0f / colsum[row];
    float u = upraw[row * 128 + t] * inv;
    float h = slots_in[row * 128 + t];
    su[t] = u; sh[t] = h;
    __syncthreads();
    float gx[3], gh[3];
    #pragma unroll
    for (int p = 0; p < 3; ++p) {
        int o = p * 128 + t;
        const float4* wi = (const float4*)(Wih + o * 128);
        const float4* wh = (const float4*)(Whh + o * 128);
        float ax = 0.f, ah = 0.f;
        #pragma unroll 8
        for (int j = 0; j < 32; ++j) {
            float4 a = wi[j], bb = wh[j];
            float4 uu = *(const float4*)(su + 4 * j);
            float4 hh = *(const float4*)(sh + 4 * j);
            ax += a.x * uu.x + a.y * uu.y + a.z * uu.z + a.w * uu.w;
            ah += bb.x * hh.x + bb.y * hh.y + bb.z * hh.z + bb.w * hh.w;
        }
        gx[p] = ax + bih[o];
        gh[p] = ah + bhh[o];
    }
    float r = 1.f / (1.f + __expf(-(gx[0] + gh[0])));
    float z = 1.f / (1.f + __expf(-(gx[1] + gh[1])));
    float n = tanhf(gx[2] + r * gh[2]);
    float hn = (1.f - z) * n + z * h;
    float sv = hn;
    #pragma unroll
    for (int m = 1; m < 64; m <<= 1) sv += __shfl_xor(sv, m);
    if ((t & 63) == 0) red[t >> 6] = sv;
    __syncthreads();
    float mean = (red[0] + red[1]) * (1.0f / 128.0f);
    __syncthreads();
    float dv = hn - mean, sq = dv * dv;
    #pragma unroll
    for (int m = 1; m < 64; m <<= 1) sq += __shfl_xor(sq, m);
    if ((t & 63) == 0) red[t >> 6] = sq;
    __syncthreads();
    float var = (red[0] + red[1]) * (1.0f / 128.0f);
    float sl = dv * rsqrtf(var + LN_EPS_) * gm[t] + bm[t];
    ssl[t] = sl;
    __syncthreads();
    #pragma unroll
    for (int p = 0; p < 2; ++p) {
        int o = p * 128 + t;
        const float4* w1r = (const float4*)(W1 + o * 128);
        float a1 = 0.f;
        #pragma unroll 8
        for (int j = 0; j < 32; ++j) {
            float4 w = w1r[j];
            float4 s4 = *(const float4*)(ssl + 4 * j);
            a1 += w.x * s4.x + w.y * s4.y + w.z * s4.z + w.w * s4.w;
        }
        shid[o] = fmaxf(a1 + b1[o], 0.f);
    }
    __syncthreads();
    const float4* w2r = (const float4*)(W2 + t * 256);
    float a2 = 0.f;
    #pragma unroll 8
    for (int j = 0; j < 64; ++j) {
        float4 w = w2r[j];
        float4 h4 = *(const float4*)(shid + 4 * j);
        a2 += w.x * h4.x + w.y * h4.y + w.z * h4.z + w.w * h4.w;
    }
    dst[row * 128 + t] = sl + a2 + b2[t];
}

// ---------------------------------------------------------------------------
extern "C" void kernel_launch(void* const* d_in, const int* in_sizes, int n_in,
                              void* d_out, int out_size, void* d_ws, size_t ws_size,
                              hipStream_t stream) {
    const float* x    = (const float*)d_in[0];
    const float* nz   = (const float*)d_in[1];
    const float* Wq   = (const float*)d_in[2];
    const float* Wk   = (const float*)d_in[3];
    const float* Wv   = (const float*)d_in[4];
    const float* ling = (const float*)d_in[5];
    const float* linb = (const float*)d_in[6];
    const float* lsg  = (const float*)d_in[7];
    const float* lsb  = (const float*)d_in[8];
    const float* lmg  = (const float*)d_in[9];
    const float* lmb  = (const float*)d_in[10];
    const float* Wih  = (const float*)d_in[11];
    const float* Whh  = (const float*)d_in[12];
    const float* bih  = (const float*)d_in[13];
    const float* bhh  = (const float*)d_in[14];
    const float* W1   = (const float*)d_in[15];
    const float* b1   = (const float*)d_in[16];
    const float* W2   = (const float*)d_in[17];
    const float* b2   = (const float*)d_in[18];
    const float* mu   = (const float*)d_in[19];
    const float* lsig = (const float*)d_in[20];

    char* wsb = (char*)d_ws;
    uint16_t* kbf   = (uint16_t*)(wsb);                        // 67108864 B
    uint16_t* vbf_t = (uint16_t*)(wsb + (size_t)67108864);     // 67108864 B
    uint16_t* Wsw   = (uint16_t*)(wsb + (size_t)134217728);    // 65536 B
    uint16_t* qbf   = (uint16_t*)(wsb + (size_t)134283264);    // 262144 B
    float*    slots = (float*)  (wsb + (size_t)134545408);     // 229376 B
    float*    csum  = (float*)  (wsb + (size_t)134774784);     // 2048 B
    float*    upraw = (float*)  (wsb + (size_t)134776832);     // 229376 B

    k_prep<<<512, 256, 0, stream>>>(nz, Wk, Wv, mu, lsig, Wsw, slots, qbf);
    k_proj<<<4096, 256, 0, stream>>>(x, Wsw, ling, linb, kbf, vbf_t);
    for (int it = 0; it < 3; ++it) {
        float* dst = (it == 2) ? (float*)d_out : slots;
        k_slotq<<<448, 128, 0, stream>>>(slots, Wq, lsg, lsb, qbf, csum, upraw);
        k_attn<<<1024, 256, 0, stream>>>(kbf, vbf_t, qbf, csum, upraw);
        k_gru_mlp<<<448, 128, 0, stream>>>(upraw, csum, slots, Wih, Whh, bih, bhh,
                                           lmg, lmb, W1, b1, W2, b2, dst);
    }
}

// Round 3
// 427.825 us; speedup vs baseline: 1.1199x; 1.1199x over previous
//
#include <hip/hip_runtime.h>
#include <hip/hip_bf16.h>
#include <stdint.h>

#define B_ 64
#define N_ 4096
#define D_ 128
#define S_ 7
#define EPS_ 1e-8f
#define LN_EPS_ 1e-5f

typedef float  f32x4  __attribute__((ext_vector_type(4)));
typedef __bf16 bf16x8 __attribute__((ext_vector_type(8)));

__device__ __forceinline__ uint16_t f2bfbits(float f) {
    uint32_t x = __float_as_uint(f);
    return (uint16_t)((x + 0x7fffu + ((x >> 16) & 1u)) >> 16);  // RNE
}
__device__ __forceinline__ uint32_t pk2(float a, float b) {
    return (uint32_t)f2bfbits(a) | ((uint32_t)f2bfbits(b) << 16);
}
__device__ __forceinline__ bf16x8 ldfrag_w(const float* wp) {
    f32x4 w0 = *(const f32x4*)wp, w1 = *(const f32x4*)(wp + 4);
    bf16x8 r;
    #pragma unroll
    for (int c = 0; c < 4; ++c) { r[c] = (__bf16)w0[c]; r[4 + c] = (__bf16)w1[c]; }
    return r;
}

// ---------------------------------------------------------------------------
// K0: slots = mu + (softplus(logsigma)+1e-5)*noise; zero padded q rows;
//     Wsw = [Wk;Wv] in MFMA fragment-linear order.
// ---------------------------------------------------------------------------
__global__ void k_prep(const float* __restrict__ noise, const float* __restrict__ Wk,
                       const float* __restrict__ Wv, const float* __restrict__ mu,
                       const float* __restrict__ logsigma,
                       uint16_t* __restrict__ Wsw, float* __restrict__ slots,
                       uint16_t* __restrict__ qbf) {
    int tid = blockIdx.x * 256 + threadIdx.x;
    if (tid < B_ * 16 * D_) qbf[tid] = 0;
    if (tid < B_ * S_ * D_) {
        int d = tid & (D_ - 1);
        float sc = log1pf(__expf(logsigma[d])) + 1e-5f;
        slots[tid] = mu[d] + sc * noise[tid];
    }
    if (tid < 32768) {
        int j = tid & 7, ch = tid >> 3;
        int lane = ch & 63, k0 = (ch >> 6) & 3, wt = (ch >> 8) & 7, h = ch >> 11;
        int row = wt * 16 + (lane & 15);
        int col = k0 * 32 + (lane >> 4) * 8 + j;
        float w = h ? Wv[row * 128 + col] : Wk[row * 128 + col];
        Wsw[tid] = f2bfbits(w);
    }
}

// ---------------------------------------------------------------------------
// K1: LN(x) in registers -> bf16 B-frags; K-half: C=Wk*xn^T -> kbf[row][d];
//     V-half: C=xn*Wv^T -> vbf_t[b][d][n]. 512 thr / 8 waves / 128 rows.
// ---------------------------------------------------------------------------
__global__ __launch_bounds__(512) void k_proj(
    const float* __restrict__ x, const uint16_t* __restrict__ Wsw,
    const float* __restrict__ lng, const float* __restrict__ lnb,
    uint16_t* __restrict__ kbf, uint16_t* __restrict__ vbf_t) {
    __shared__ __align__(16) uint16_t wlds[16384];  // 32 KB, frag-linear
    const int t = threadIdx.x, wv = t >> 6, lane = t & 63;
    const int lm = lane & 15, qd = lane >> 4;
    const long row0 = (long)blockIdx.x * 128;
    const int b = (int)(row0 >> 12);
    const int nloc = (int)(row0 & 4095);

    uint4 wst[4];
    #pragma unroll
    for (int i = 0; i < 4; ++i)
        wst[i] = *(const uint4*)(Wsw + (i * 512 + t) * 8);

    const long xrow = row0 + wv * 16 + lm;
    const float* xp = x + xrow * 128 + qd * 8;
    f32x4 xa[8];
    #pragma unroll
    for (int k0 = 0; k0 < 4; ++k0) {
        xa[2 * k0]     = *(const f32x4*)(xp + k0 * 32);
        xa[2 * k0 + 1] = *(const f32x4*)(xp + k0 * 32 + 4);
    }
    #pragma unroll
    for (int i = 0; i < 4; ++i)
        *(uint4*)(wlds + (i * 512 + t) * 8) = wst[i];

    float s = 0.f, sq = 0.f;
    #pragma unroll
    for (int i = 0; i < 8; ++i)
        #pragma unroll
        for (int c = 0; c < 4; ++c) { float v = xa[i][c]; s += v; sq += v * v; }
    s  += __shfl_xor(s, 16);  s  += __shfl_xor(s, 32);
    sq += __shfl_xor(sq, 16); sq += __shfl_xor(sq, 32);
    float mean = s * (1.0f / 128.0f);
    float var  = sq * (1.0f / 128.0f) - mean * mean;
    float rs   = rsqrtf(var + LN_EPS_);

    bf16x8 xf[4];
    #pragma unroll
    for (int k0 = 0; k0 < 4; ++k0) {
        const float* gp = lng + k0 * 32 + qd * 8;
        const float* bp = lnb + k0 * 32 + qd * 8;
        f32x4 g0 = *(const f32x4*)(gp), g1 = *(const f32x4*)(gp + 4);
        f32x4 b0 = *(const f32x4*)(bp), b1 = *(const f32x4*)(bp + 4);
        #pragma unroll
        for (int c = 0; c < 4; ++c) {
            xf[k0][c]     = (__bf16)((xa[2 * k0][c]     - mean) * rs * g0[c] + b0[c]);
            xf[k0][4 + c] = (__bf16)((xa[2 * k0 + 1][c] - mean) * rs * g1[c] + b1[c]);
        }
    }
    __syncthreads();

    #pragma unroll
    for (int mt = 0; mt < 8; ++mt) {
        f32x4 acc = {0.f, 0.f, 0.f, 0.f};
        #pragma unroll
        for (int k0 = 0; k0 < 4; ++k0) {
            bf16x8 wf = *(const bf16x8*)(wlds + ((mt * 4 + k0) * 64 + lane) * 8);
            acc = __builtin_amdgcn_mfma_f32_16x16x32_bf16(wf, xf[k0], acc, 0, 0, 0);
        }
        uint2 st; st.x = pk2(acc[0], acc[1]); st.y = pk2(acc[2], acc[3]);
        *(uint2*)(kbf + (row0 + wv * 16 + lm) * 128 + mt * 16 + qd * 4) = st;
    }
    __syncthreads();

    #pragma unroll
    for (int i = 0; i < 4; ++i)
        wst[i] = *(const uint4*)(Wsw + 16384 + (i * 512 + t) * 8);
    #pragma unroll
    for (int i = 0; i < 4; ++i)
        *(uint4*)(wlds + (i * 512 + t) * 8) = wst[i];
    __syncthreads();

    #pragma unroll
    for (int nt = 0; nt < 8; ++nt) {
        f32x4 acc = {0.f, 0.f, 0.f, 0.f};
        #pragma unroll
        for (int k0 = 0; k0 < 4; ++k0) {
            bf16x8 wf = *(const bf16x8*)(wlds + ((nt * 4 + k0) * 64 + lane) * 8);
            acc = __builtin_amdgcn_mfma_f32_16x16x32_bf16(xf[k0], wf, acc, 0, 0, 0);
        }
        uint2 st; st.x = pk2(acc[0], acc[1]); st.y = pk2(acc[2], acc[3]);
        *(uint2*)(vbf_t + ((long)(b * 128 + nt * 16 + lm)) * 4096 + nloc + wv * 16 + qd * 4) = st;
    }
}

// ---------------------------------------------------------------------------
// K2: initial q only: sn = LN(slots); q = (sn @ Wq^T) * D^-1/2 -> bf16.
// ---------------------------------------------------------------------------
__global__ __launch_bounds__(128) void k_slotq(
    const float* __restrict__ slots, const float* __restrict__ Wq,
    const float* __restrict__ g, const float* __restrict__ bt,
    uint16_t* __restrict__ qbf) {
    int row = blockIdx.x;  // b*7 + s
    int b = row / 7, s = row - b * 7;
    int t = threadIdx.x;
    __shared__ float sn[128];
    __shared__ float red[2];
    float v = slots[row * 128 + t];
    float sv = v;
    #pragma unroll
    for (int m = 1; m < 64; m <<= 1) sv += __shfl_xor(sv, m);
    if ((t & 63) == 0) red[t >> 6] = sv;
    __syncthreads();
    float mean = (red[0] + red[1]) * (1.0f / 128.0f);
    __syncthreads();
    float dv = v - mean, sq = dv * dv;
    #pragma unroll
    for (int m = 1; m < 64; m <<= 1) sq += __shfl_xor(sq, m);
    if ((t & 63) == 0) red[t >> 6] = sq;
    __syncthreads();
    float var = (red[0] + red[1]) * (1.0f / 128.0f);
    sn[t] = dv * rsqrtf(var + LN_EPS_) * g[t] + bt[t];
    __syncthreads();
    const float4* wr = (const float4*)(Wq + t * 128);
    float acc = 0.f;
    #pragma unroll 8
    for (int j = 0; j < 32; ++j) {
        float4 w = wr[j];
        float4 s4 = *(const float4*)(sn + 4 * j);
        acc += w.x * s4.x + w.y * s4.y + w.z * s4.z + w.w * s4.w;
    }
    qbf[(b * 16 + s) * 128 + t] = f2bfbits(acc * 0.08838834764831843f);
}

// ---------------------------------------------------------------------------
// K3: scores (MFMA) -> softmax over S=7 -> bf16 attn frags in LDS ->
//     updates = v^T*attn (MFMA) -> per-block partials (NO atomics).
//     512 thr / 8 waves; grid = b*8 + chunk.
// ---------------------------------------------------------------------------
__global__ __launch_bounds__(512) void k_attn(
    const uint16_t* __restrict__ kbf, const uint16_t* __restrict__ vbf_t,
    const uint16_t* __restrict__ qbf,
    float* __restrict__ upart, float* __restrict__ cpart) {
    __shared__ __align__(16) uint16_t als[8][1024];
    __shared__ __align__(16) float part[8][7][132];
    __shared__ float bsum[8][8];
    const int t = threadIdx.x, wv = t >> 6, lane = t & 63;
    const int lm = lane & 15, qd = lane >> 4;
    const int b = blockIdx.x >> 3, chunk = blockIdx.x & 7;
    const int rb = chunk * 512 + wv * 64;
    const long gbase = (long)b * N_ + rb;

    bf16x8 bq[4];
    #pragma unroll
    for (int k0 = 0; k0 < 4; ++k0)
        bq[k0] = *(const bf16x8*)(qbf + b * 2048 + lm * 128 + k0 * 32 + qd * 8);

    float csl = 0.f;
    #pragma unroll
    for (int mt = 0; mt < 4; ++mt) {
        f32x4 acc = {0.f, 0.f, 0.f, 0.f};
        long rr = gbase + mt * 16;
        #pragma unroll
        for (int k0 = 0; k0 < 4; ++k0) {
            bf16x8 a = *(const bf16x8*)(kbf + (rr + lm) * 128 + k0 * 32 + qd * 8);
            acc = __builtin_amdgcn_mfma_f32_16x16x32_bf16(a, bq[k0], acc, 0, 0, 0);
        }
        uint16_t pb[4];
        #pragma unroll
        for (int r = 0; r < 4; ++r) {
            float sc = acc[r];
            float scm = (lm < 7) ? sc : -1e30f;
            #pragma unroll
            for (int m = 1; m < 16; m <<= 1) scm = fmaxf(scm, __shfl_xor(scm, m));
            float e = (lm < 7) ? __expf(sc - scm) : 0.f;
            float tot = e;
            #pragma unroll
            for (int m = 1; m < 16; m <<= 1) tot += __shfl_xor(tot, m);
            float a_ = e / tot + EPS_;
            if (lm < 7) csl += a_;
            pb[r] = f2bfbits(a_);
        }
        int elem = (mt >> 1) * 512 + (((mt & 1) * 2 + (qd >> 1)) * 16 + lm) * 8 + (qd & 1) * 4;
        uint2 pw; pw.x = (uint32_t)pb[0] | ((uint32_t)pb[1] << 16);
        pw.y = (uint32_t)pb[2] | ((uint32_t)pb[3] << 16);
        *(uint2*)(&als[wv][elem]) = pw;
    }
    csl += __shfl_xor(csl, 16); csl += __shfl_xor(csl, 32);
    if (lane < 7) bsum[wv][lane] = csl;
    __syncthreads();

    bf16x8 afr0 = *(const bf16x8*)(&als[wv][lane * 8]);
    bf16x8 afr1 = *(const bf16x8*)(&als[wv][512 + lane * 8]);
    f32x4 uacc[8];
    #pragma unroll
    for (int i = 0; i < 8; ++i) uacc[i] = (f32x4){0.f, 0.f, 0.f, 0.f};
    #pragma unroll
    for (int nt = 0; nt < 8; ++nt) {
        const uint16_t* vp = vbf_t + ((long)(b * 128 + nt * 16 + lm)) * 4096 + rb;
        bf16x8 v0 = *(const bf16x8*)(vp + qd * 8);
        bf16x8 v1 = *(const bf16x8*)(vp + 32 + qd * 8);
        uacc[nt] = __builtin_amdgcn_mfma_f32_16x16x32_bf16(v0, afr0, uacc[nt], 0, 0, 0);
        uacc[nt] = __builtin_amdgcn_mfma_f32_16x16x32_bf16(v1, afr1, uacc[nt], 0, 0, 0);
    }
    if (lm < 7) {
        #pragma unroll
        for (int nt = 0; nt < 8; ++nt)
            *(f32x4*)&part[wv][lm][nt * 16 + qd * 4] = uacc[nt];
    }
    __syncthreads();
    if (t < 128) {
        #pragma unroll
        for (int s = 0; s < 7; ++s) {
            float v = 0.f;
            #pragma unroll
            for (int w = 0; w < 8; ++w) v += part[w][s][t];
            upart[((b * 8 + chunk) * 7 + s) * 128 + t] = v;
        }
    }
    if (t < 7) {
        float c = 0.f;
        #pragma unroll
        for (int w = 0; w < 8; ++w) c += bsum[w][t];
        cpart[(b * 8 + chunk) * 7 + t] = c;
    }
}

// ---------------------------------------------------------------------------
// K4 (fused, one block per batch b, 256 thr / 4 waves):
//   reduce partials -> u; GRU via MFMA; LN; MLP via MFMA; write slots/dst;
//   if hasq: LN + q-proj via MFMA for next iteration.
// ---------------------------------------------------------------------------
__global__ __launch_bounds__(256) void k_fused(
    const float* __restrict__ upart, const float* __restrict__ cpart,
    float* __restrict__ slots,
    const float* __restrict__ Wih, const float* __restrict__ Whh,
    const float* __restrict__ bih, const float* __restrict__ bhh,
    const float* __restrict__ gm, const float* __restrict__ bm,
    const float* __restrict__ W1, const float* __restrict__ b1,
    const float* __restrict__ W2, const float* __restrict__ b2,
    const float* __restrict__ Wq, const float* __restrict__ lsg,
    const float* __restrict__ lsb,
    uint16_t* __restrict__ qbf, float* __restrict__ dst, int hasq) {
    __shared__ float uf[16][132];     // u, later hn, later sn
    __shared__ float hf[16][132];     // h, later out
    __shared__ float slf[16][132];    // LN(hn)
    __shared__ float hidl[16][264];   // MLP hidden
    __shared__ float glg[7][776];     // [s][0:384)=gx, [384:768)=gh
    __shared__ float csl[7];
    const int b = blockIdx.x;
    const int t = threadIdx.x, wv = t >> 6, lane = t & 63;
    const int lm = lane & 15, qd = lane >> 4;

    if (t < 7) {
        float c = 0.f;
        #pragma unroll
        for (int i = 0; i < 8; ++i) c += cpart[(b * 8 + i) * 7 + t];
        csl[t] = c;
    }
    __syncthreads();
    for (int idx = t; idx < 896; idx += 256) {
        int s = idx >> 7, d = idx & 127;
        float acc = 0.f;
        #pragma unroll
        for (int i = 0; i < 8; ++i) acc += upart[((b * 8 + i) * 7 + s) * 128 + d];
        uf[s][d] = acc / csl[s];
        hf[s][d] = slots[(b * 7 + s) * 128 + d];
    }
    __syncthreads();

    bf16x8 au[4], ah[4];
    #pragma unroll
    for (int k0 = 0; k0 < 4; ++k0)
        #pragma unroll
        for (int j = 0; j < 8; ++j) {
            au[k0][j] = (__bf16)uf[lm][k0 * 32 + qd * 8 + j];
            ah[k0][j] = (__bf16)hf[lm][k0 * 32 + qd * 8 + j];
        }

    // GRU gates: waves 0-1 -> gx (24 tiles of Wih), waves 2-3 -> gh (Whh)
    {
        const int ih = (wv < 2);
        const float* W = ih ? Wih : Whh;
        const int base = ih ? 0 : 384;
        const int w2 = wv & 1;
        #pragma unroll
        for (int i = 0; i < 12; ++i) {
            int o0 = (w2 * 12 + i) * 16;
            f32x4 acc = {0.f, 0.f, 0.f, 0.f};
            #pragma unroll
            for (int k0 = 0; k0 < 4; ++k0) {
                bf16x8 bf = ldfrag_w(W + (o0 + lm) * 128 + k0 * 32 + qd * 8);
                acc = __builtin_amdgcn_mfma_f32_16x16x32_bf16(ih ? au[k0] : ah[k0], bf, acc, 0, 0, 0);
            }
            #pragma unroll
            for (int r = 0; r < 4; ++r) {
                int s = qd * 4 + r;
                if (s < 7) glg[s][base + o0 + lm] = acc[r];
            }
        }
    }
    __syncthreads();

    // elementwise GRU -> hn in uf
    for (int idx = t; idx < 896; idx += 256) {
        int s = idx >> 7, d = idx & 127;
        float xr = glg[s][d] + bih[d];
        float xz = glg[s][128 + d] + bih[128 + d];
        float xn = glg[s][256 + d] + bih[256 + d];
        float hr = glg[s][384 + d] + bhh[d];
        float hz = glg[s][512 + d] + bhh[128 + d];
        float hnn = glg[s][640 + d] + bhh[256 + d];
        float r = 1.f / (1.f + __expf(-(xr + hr)));
        float z = 1.f / (1.f + __expf(-(xz + hz)));
        float n = tanhf(xn + r * hnn);
        uf[s][d] = (1.f - z) * n + z * hf[s][d];
    }
    __syncthreads();

    // LN(hn) -> slf
    for (int s = wv; s < 7; s += 4) {
        float a0 = uf[s][2 * lane], a1 = uf[s][2 * lane + 1];
        float sm = a0 + a1, sq = a0 * a0 + a1 * a1;
        #pragma unroll
        for (int m = 1; m < 64; m <<= 1) { sm += __shfl_xor(sm, m); sq += __shfl_xor(sq, m); }
        float mean = sm * (1.0f / 128.0f);
        float var = sq * (1.0f / 128.0f) - mean * mean;
        float rs = rsqrtf(var + LN_EPS_);
        slf[s][2 * lane]     = (a0 - mean) * rs * gm[2 * lane] + bm[2 * lane];
        slf[s][2 * lane + 1] = (a1 - mean) * rs * gm[2 * lane + 1] + bm[2 * lane + 1];
    }
    __syncthreads();

    // MLP1: hid = relu(sl @ W1^T + b1), 16 n-tiles
    bf16x8 as_[4];
    #pragma unroll
    for (int k0 = 0; k0 < 4; ++k0)
        #pragma unroll
        for (int j = 0; j < 8; ++j) as_[k0][j] = (__bf16)slf[lm][k0 * 32 + qd * 8 + j];
    #pragma unroll
    for (int i = 0; i < 4; ++i) {
        int o0 = (wv * 4 + i) * 16;
        f32x4 acc = {0.f, 0.f, 0.f, 0.f};
        #pragma unroll
        for (int k0 = 0; k0 < 4; ++k0) {
            bf16x8 bf = ldfrag_w(W1 + (o0 + lm) * 128 + k0 * 32 + qd * 8);
            acc = __builtin_amdgcn_mfma_f32_16x16x32_bf16(as_[k0], bf, acc, 0, 0, 0);
        }
        #pragma unroll
        for (int r = 0; r < 4; ++r) {
            int s = qd * 4 + r;
            if (s < 7) hidl[s][o0 + lm] = fmaxf(acc[r] + b1[o0 + lm], 0.f);
        }
    }
    __syncthreads();

    // MLP2: out = sl + hid @ W2^T + b2, 8 n-tiles, K=256
    bf16x8 ahd[8];
    #pragma unroll
    for (int k0 = 0; k0 < 8; ++k0)
        #pragma unroll
        for (int j = 0; j < 8; ++j) ahd[k0][j] = (__bf16)hidl[lm][k0 * 32 + qd * 8 + j];
    #pragma unroll
    for (int i = 0; i < 2; ++i) {
        int o0 = (wv * 2 + i) * 16;
        f32x4 acc = {0.f, 0.f, 0.f, 0.f};
        #pragma unroll
        for (int k0 = 0; k0 < 8; ++k0) {
            bf16x8 bf = ldfrag_w(W2 + (o0 + lm) * 256 + k0 * 32 + qd * 8);
            acc = __builtin_amdgcn_mfma_f32_16x16x32_bf16(ahd[k0], bf, acc, 0, 0, 0);
        }
        #pragma unroll
        for (int r = 0; r < 4; ++r) {
            int s = qd * 4 + r;
            if (s < 7) {
                float v = slf[s][o0 + lm] + acc[r] + b2[o0 + lm];
                hf[s][o0 + lm] = v;
                dst[(b * 7 + s) * 128 + o0 + lm] = v;
            }
        }
    }
    if (hasq) {
        __syncthreads();
        for (int s = wv; s < 7; s += 4) {
            float a0 = hf[s][2 * lane], a1 = hf[s][2 * lane + 1];
            float sm = a0 + a1, sq = a0 * a0 + a1 * a1;
            #pragma unroll
            for (int m = 1; m < 64; m <<= 1) { sm += __shfl_xor(sm, m); sq += __shfl_xor(sq, m); }
            float mean = sm * (1.0f / 128.0f);
            float var = sq * (1.0f / 128.0f) - mean * mean;
            float rs = rsqrtf(var + LN_EPS_);
            uf[s][2 * lane]     = (a0 - mean) * rs * lsg[2 * lane] + lsb[2 * lane];
            uf[s][2 * lane + 1] = (a1 - mean) * rs * lsg[2 * lane + 1] + lsb[2 * lane + 1];
        }
        __syncthreads();
        bf16x8 an[4];
        #pragma unroll
        for (int k0 = 0; k0 < 4; ++k0)
            #pragma unroll
            for (int j = 0; j < 8; ++j) an[k0][j] = (__bf16)uf[lm][k0 * 32 + qd * 8 + j];
        #pragma unroll
        for (int i = 0; i < 2; ++i) {
            int o0 = (wv * 2 + i) * 16;
            f32x4 acc = {0.f, 0.f, 0.f, 0.f};
            #pragma unroll
            for (int k0 = 0; k0 < 4; ++k0) {
                bf16x8 bf = ldfrag_w(Wq + (o0 + lm) * 128 + k0 * 32 + qd * 8);
                acc = __builtin_amdgcn_mfma_f32_16x16x32_bf16(an[k0], bf, acc, 0, 0, 0);
            }
            #pragma unroll
            for (int r = 0; r < 4; ++r) {
                int s = qd * 4 + r;
                if (s < 7)
                    qbf[(b * 16 + s) * 128 + o0 + lm] = f2bfbits(acc[r] * 0.08838834764831843f);
            }
        }
    }
}

// ---------------------------------------------------------------------------
extern "C" void kernel_launch(void* const* d_in, const int* in_sizes, int n_in,
                              void* d_out, int out_size, void* d_ws, size_t ws_size,
                              hipStream_t stream) {
    const float* x    = (const float*)d_in[0];
    const float* nz   = (const float*)d_in[1];
    const float* Wq   = (const float*)d_in[2];
    const float* Wk   = (const float*)d_in[3];
    const float* Wv   = (const float*)d_in[4];
    const float* ling = (const float*)d_in[5];
    const float* linb = (const float*)d_in[6];
    const float* lsg  = (const float*)d_in[7];
    const float* lsb  = (const float*)d_in[8];
    const float* lmg  = (const float*)d_in[9];
    const float* lmb  = (const float*)d_in[10];
    const float* Wih  = (const float*)d_in[11];
    const float* Whh  = (const float*)d_in[12];
    const float* bih  = (const float*)d_in[13];
    const float* bhh  = (const float*)d_in[14];
    const float* W1   = (const float*)d_in[15];
    const float* b1   = (const float*)d_in[16];
    const float* W2   = (const float*)d_in[17];
    const float* b2   = (const float*)d_in[18];
    const float* mu   = (const float*)d_in[19];
    const float* lsig = (const float*)d_in[20];

    char* wsb = (char*)d_ws;
    uint16_t* kbf   = (uint16_t*)(wsb);                        // 67108864 B
    uint16_t* vbf_t = (uint16_t*)(wsb + (size_t)67108864);     // 67108864 B
    uint16_t* Wsw   = (uint16_t*)(wsb + (size_t)134217728);    // 65536 B
    uint16_t* qbf   = (uint16_t*)(wsb + (size_t)134283264);    // 262144 B
    float*    slots = (float*)  (wsb + (size_t)134545408);     // 229376 B
    float*    upart = (float*)  (wsb + (size_t)134774784);     // 1835008 B
    float*    cpart = (float*)  (wsb + (size_t)136609792);     // 14336 B

    k_prep<<<512, 256, 0, stream>>>(nz, Wk, Wv, mu, lsig, Wsw, slots, qbf);
    k_proj<<<2048, 512, 0, stream>>>(x, Wsw, ling, linb, kbf, vbf_t);
    k_slotq<<<448, 128, 0, stream>>>(slots, Wq, lsg, lsb, qbf);
    for (int it = 0; it < 3; ++it) {
        float* dst = (it == 2) ? (float*)d_out : slots;
        k_attn<<<512, 512, 0, stream>>>(kbf, vbf_t, qbf, upart, cpart);
        k_fused<<<64, 256, 0, stream>>>(upart, cpart, slots, Wih, Whh, bih, bhh,
                                        lmg, lmb, W1, b1, W2, b2, Wq, lsg, lsb,
                                        qbf, dst, (it < 2) ? 1 : 0);
    }
}